// Round 1
// baseline (122.855 us; speedup 1.0000x reference)
//
#include <hip/hip_runtime.h>

#define DD 1024

// In-register FWHT over 16 values (strides 1,2,4,8 in the register index).
__device__ __forceinline__ void fwht16(float (&v)[16]) {
  #pragma unroll
  for (int h = 1; h < 16; h <<= 1) {
    #pragma unroll
    for (int i = 0; i < 16; ++i) {
      if (!(i & h)) {
        float a = v[i], b = v[i | h];
        v[i]     = a + b;
        v[i | h] = a - b;
      }
    }
  }
}

// Cross-lane butterfly: pairs (lane, lane^mask); lower lane gets a+b, upper a-b.
__device__ __forceinline__ void shfl_stage(float (&v)[16], int mask, int lane) {
  const float sgn = (lane & mask) ? -1.0f : 1.0f;
  #pragma unroll
  for (int j = 0; j < 16; ++j) {
    float o = __shfl_xor(v[j], mask, 64);
    v[j] = fmaf(sgn, v[j], o);  // lower: o + v = a+b ; upper: o - v = a-b
  }
}

// One wave per row. Lane holds 16 fp32.
// Layout A (contiguous): e = 16*lane + j   -> strides 1..8 intra, 16/32 via shfl
// Layout B (strided):    e = lane + 64*k   -> strides 64..512 intra
// LDS transpose uses padded index e + e/32: exactly 2 lanes/bank (free, m136).
__global__ __launch_bounds__(256) void srht_kernel(
    const float* __restrict__ x,
    const float* __restrict__ signs,
    float* __restrict__ out)
{
  __shared__ float lds[4][DD + DD / 32];  // 4 waves/block, 4224 B per row
  const int lane = threadIdx.x & 63;
  const int wv   = threadIdx.x >> 6;
  const long row = (long)blockIdx.x * 4 + wv;

  const float* __restrict__ xr = x + row * DD;
  float* __restrict__ orow     = out + row * DD;
  const float* __restrict__ s0 = signs;
  const float* __restrict__ s1 = signs + DD;
  float* buf = lds[wv];

  float v[16];

  // ---- load contiguous (e = 16*lane + j), apply sign0 ----
  {
    const float4* xp = (const float4*)(xr + 16 * lane);
    const float4* sp = (const float4*)(s0 + 16 * lane);
    #pragma unroll
    for (int c = 0; c < 4; ++c) {
      float4 a = xp[c], s = sp[c];
      v[4 * c + 0] = a.x * s.x;
      v[4 * c + 1] = a.y * s.y;
      v[4 * c + 2] = a.z * s.z;
      v[4 * c + 3] = a.w * s.w;
    }
  }

  // ---- pass 1 ----
  fwht16(v);               // h = 1,2,4,8
  shfl_stage(v, 1, lane);  // h = 16
  shfl_stage(v, 2, lane);  // h = 32

  // transpose A -> B
  {
    const int wb = 16 * lane + (lane >> 1);   // pad(16*lane + j) = wb + j
    #pragma unroll
    for (int j = 0; j < 16; ++j) buf[wb + j] = v[j];
  }
  __syncthreads();
  {
    const int rb = lane + (lane >> 5);        // pad(lane + 64k) = rb + 66k
    #pragma unroll
    for (int k = 0; k < 16; ++k) v[k] = buf[rb + 66 * k];
  }
  fwht16(v);               // h = 64,128,256,512  — pass 1 complete

  // ---- between passes: * sign1 * (1/32) ----
  #pragma unroll
  for (int k = 0; k < 16; ++k)
    v[k] *= s1[lane + 64 * k] * 0.03125f;

  // ---- pass 2 (stages commute; run in reverse order) ----
  fwht16(v);               // h = 64,128,256,512
  __syncthreads();
  // transpose B -> A
  {
    const int wb = lane + (lane >> 5);
    #pragma unroll
    for (int k = 0; k < 16; ++k) buf[wb + 66 * k] = v[k];
  }
  __syncthreads();
  {
    const int rb = 16 * lane + (lane >> 1);
    #pragma unroll
    for (int j = 0; j < 16; ++j) v[j] = buf[rb + j];
  }
  shfl_stage(v, 1, lane);  // h = 16
  shfl_stage(v, 2, lane);  // h = 32
  fwht16(v);               // h = 1,2,4,8

  // ---- store contiguous, * (1/32) ----
  {
    float4* op = (float4*)(orow + 16 * lane);
    #pragma unroll
    for (int c = 0; c < 4; ++c) {
      float4 r;
      r.x = v[4 * c + 0] * 0.03125f;
      r.y = v[4 * c + 1] * 0.03125f;
      r.z = v[4 * c + 2] * 0.03125f;
      r.w = v[4 * c + 3] * 0.03125f;
      op[c] = r;
    }
  }
}

extern "C" void kernel_launch(void* const* d_in, const int* in_sizes, int n_in,
                              void* d_out, int out_size, void* d_ws, size_t ws_size,
                              hipStream_t stream) {
  const float* x     = (const float*)d_in[0];
  const float* signs = (const float*)d_in[1];
  float* out         = (float*)d_out;

  const int rows   = in_sizes[0] / DD;  // 8*8192 = 65536
  const int blocks = rows / 4;          // 4 rows (waves) per 256-thread block

  hipLaunchKernelGGL(srht_kernel, dim3(blocks), dim3(256), 0, stream,
                     x, signs, out);
}